// Round 1
// baseline (670.069 us; speedup 1.0000x reference)
//
#include <hip/hip_runtime.h>
#include <hip/hip_bf16.h>
#include <math.h>

#define NTOK 16384
#define HDIM 4096
#define NEXP 64

// ---------------- W transpose: [64][4096] -> Wt [4096][64] ----------------
__global__ __launch_bounds__(256) void transpose_w(const float* __restrict__ W,
                                                   float* __restrict__ Wt) {
  __shared__ float tile[64][65];
  const int kc = blockIdx.x * 64;
  const int t = threadIdx.x;
#pragma unroll
  for (int i = 0; i < 16; ++i) {
    int q = t + i * 256;
    int e = q >> 6, c = q & 63;
    tile[e][c] = W[(size_t)e * HDIM + kc + c];   // coalesced along k
  }
  __syncthreads();
#pragma unroll
  for (int i = 0; i < 16; ++i) {
    int q = t + i * 256;
    int k = q >> 6, e = q & 63;
    Wt[(size_t)(kc + k) * 64 + e] = tile[e][k];  // coalesced along e
  }
}

// ---------------- GEMM: logits_t[e][n] = sum_h x[n][h] * W[e][h] ----------------
// 512 WGs x 128 threads. Tile: 32 tokens x 64 experts, KC=64.
// Per thread: 4 tokens x 4 experts, fp32 chunk partials accumulated in fp64.
__global__ __launch_bounds__(128) void gemm_logits(const float* __restrict__ x,
                                                   const float* __restrict__ Wt,
                                                   float* __restrict__ logits_t) {
  __shared__ __align__(16) float xs[32][68];  // token-major, stride 68 (pad, 16B-aligned rows)
  __shared__ __align__(16) float ws[64][68];  // k-major, experts contiguous
  const int t = threadIdx.x;
  const int tx = t & 15, ty = t >> 4;   // tx: expert group, ty: token group (0..7)
  const int tok0 = blockIdx.x * 32;
  const int e0 = tx * 4;

  float4 vx[4], vw[8];
  // prologue: prefetch chunk 0 into registers
#pragma unroll
  for (int i = 0; i < 4; ++i) {
    int q = t + i * 128, row = q >> 4, c4 = (q & 15) << 2;
    vx[i] = *(const float4*)&x[(size_t)(tok0 + row) * HDIM + c4];
  }
#pragma unroll
  for (int i = 0; i < 8; ++i) {
    int q = t + i * 128, r = q >> 4, c4 = (q & 15) << 2;
    vw[i] = *(const float4*)&Wt[(size_t)r * 64 + c4];
  }

  double acc[4][4];
#pragma unroll
  for (int i = 0; i < 4; ++i)
#pragma unroll
    for (int j = 0; j < 4; ++j) acc[i][j] = 0.0;

  for (int kc = 0; kc < HDIM; kc += 64) {
    // store prefetched chunk to LDS
#pragma unroll
    for (int i = 0; i < 4; ++i) {
      int q = t + i * 128, row = q >> 4, c4 = (q & 15) << 2;
      *(float4*)&xs[row][c4] = vx[i];
    }
#pragma unroll
    for (int i = 0; i < 8; ++i) {
      int q = t + i * 128, r = q >> 4, c4 = (q & 15) << 2;
      *(float4*)&ws[r][c4] = vw[i];
    }
    __syncthreads();
    // prefetch next chunk (overlaps with compute below)
    if (kc + 64 < HDIM) {
#pragma unroll
      for (int i = 0; i < 4; ++i) {
        int q = t + i * 128, row = q >> 4, c4 = (q & 15) << 2;
        vx[i] = *(const float4*)&x[(size_t)(tok0 + row) * HDIM + kc + 64 + c4];
      }
#pragma unroll
      for (int i = 0; i < 8; ++i) {
        int q = t + i * 128, r = q >> 4, c4 = (q & 15) << 2;
        vw[i] = *(const float4*)&Wt[(size_t)(kc + 64 + r) * 64 + c4];
      }
    }
    // compute chunk: fresh fp32 partials (bounded magnitude -> low rounding error)
    float p[4][4];
#pragma unroll
    for (int i = 0; i < 4; ++i)
#pragma unroll
      for (int j = 0; j < 4; ++j) p[i][j] = 0.0f;

#pragma unroll
    for (int k = 0; k < 64; k += 4) {
      float4 xa[4];
#pragma unroll
      for (int i = 0; i < 4; ++i) xa[i] = *(const float4*)&xs[4 * ty + i][k];
#pragma unroll
      for (int kk = 0; kk < 4; ++kk) {
        float4 w = *(const float4*)&ws[k + kk][e0];
#pragma unroll
        for (int i = 0; i < 4; ++i) {
          float xv = ((const float*)&xa[i])[kk];
          p[i][0] = fmaf(xv, w.x, p[i][0]);
          p[i][1] = fmaf(xv, w.y, p[i][1]);
          p[i][2] = fmaf(xv, w.z, p[i][2]);
          p[i][3] = fmaf(xv, w.w, p[i][3]);
        }
      }
    }
#pragma unroll
    for (int i = 0; i < 4; ++i)
#pragma unroll
      for (int j = 0; j < 4; ++j) acc[i][j] += (double)p[i][j];
    __syncthreads();
  }

  // write expert-major logits for coalesced top-k reads
#pragma unroll
  for (int j = 0; j < 4; ++j)
#pragma unroll
    for (int i = 0; i < 4; ++i)
      logits_t[(size_t)(e0 + j) * NTOK + tok0 + 4 * ty + i] = (float)acc[i][j];
}

// ---------------- top-k + softmax + usage counts ----------------
__global__ __launch_bounds__(256) void topk_kernel(const float* __restrict__ logits_t,
                                                   float* __restrict__ out_scores,
                                                   float* __restrict__ out_idx,
                                                   unsigned int* __restrict__ counts) {
  const int n = blockIdx.x * 256 + threadIdx.x;  // token id
  __shared__ unsigned int lcnt[64];
  if (threadIdx.x < 64) lcnt[threadIdx.x] = 0u;
  __syncthreads();

  float v[8];
  int id[8];
#pragma unroll
  for (int j = 0; j < 8; ++j) { v[j] = -INFINITY; id[j] = 0; }

  for (int e = 0; e < 64; ++e) {
    float val = logits_t[(size_t)e * NTOK + n];  // coalesced
    // stable descending insert (ties keep earlier/lower index first) — static reg indices
#pragma unroll
    for (int j = 7; j >= 0; --j) {
      if (val > v[j]) {
        if (j == 0 || val <= v[j - 1]) { v[j] = val; id[j] = e; }
        else { v[j] = v[j - 1]; id[j] = id[j - 1]; }
      }
    }
  }

  // softmax over the 8 kept scores (max is v[0])
  float ex[8], s = 0.0f;
#pragma unroll
  for (int j = 0; j < 8; ++j) { ex[j] = expf(v[j] - v[0]); s += ex[j]; }
  float inv = 1.0f / s;

#pragma unroll
  for (int j = 0; j < 8; ++j) {
    out_scores[(size_t)n * 8 + j] = ex[j] * inv;
    out_idx[(size_t)n * 8 + j] = (float)id[j];
    atomicAdd(&lcnt[id[j]], 1u);
  }
  __syncthreads();
  if (threadIdx.x < 64) atomicAdd(&counts[threadIdx.x], lcnt[threadIdx.x]);
}

// ---------------- load-balance loss ----------------
__global__ __launch_bounds__(64) void loss_kernel(const unsigned int* __restrict__ counts,
                                                  float* __restrict__ out_loss) {
  const int e = threadIdx.x;  // 64 threads
  double d = (double)counts[e] / (double)NTOK - 1.0 / 64.0;
  double sq = d * d;
#pragma unroll
  for (int off = 32; off > 0; off >>= 1) sq += __shfl_down(sq, off);
  if (e == 0) *out_loss = (float)(0.01 * sq);
}

extern "C" void kernel_launch(void* const* d_in, const int* in_sizes, int n_in,
                              void* d_out, int out_size, void* d_ws, size_t ws_size,
                              hipStream_t stream) {
  const float* x = (const float*)d_in[0];   // [4,4096,4096] fp32 -> [16384][4096]
  const float* W = (const float*)d_in[1];   // [64][4096] fp32

  float* out = (float*)d_out;
  float* scores = out;                   // [16384][8]
  float* idxf = out + (size_t)NTOK * 8;  // [16384][8] indices as float
  float* loss = out + (size_t)NTOK * 16; // scalar at 262144

  // ws layout: [0,256) counts; [256, 256+1MB) Wt; then logits_t (4MB)
  unsigned int* counts = (unsigned int*)d_ws;
  float* Wt = (float*)((char*)d_ws + 256);
  float* logits_t = (float*)((char*)d_ws + 256 + (size_t)HDIM * NEXP * 4);

  hipMemsetAsync(d_ws, 0, 256, stream);  // zero the usage counts (ws is poisoned each call)
  transpose_w<<<HDIM / 64, 256, 0, stream>>>(W, Wt);
  gemm_logits<<<NTOK / 32, 128, 0, stream>>>(x, Wt, logits_t);
  topk_kernel<<<NTOK / 256, 256, 0, stream>>>(logits_t, scores, idxf, counts);
  loss_kernel<<<1, 64, 0, stream>>>(counts, loss);
}